// Round 19
// baseline (234.266 us; speedup 1.0000x reference)
//
#include <hip/hip_runtime.h>

#define SEQ   2048
#define BATCH 4
#define NH    16
#define DM    1024
#define MTOT  (BATCH*SEQ)   // 8192

typedef unsigned short u16;
typedef unsigned int   u32;
typedef __attribute__((ext_vector_type(8)))  __bf16 bf16x8;
typedef __attribute__((ext_vector_type(4)))  float  f32x4;
typedef __attribute__((ext_vector_type(16))) float  f32x16;
typedef __attribute__((address_space(1))) u32 as1_u32;
typedef __attribute__((address_space(3))) u32 as3_u32;

__device__ __forceinline__ u16 f2bf(float f) {
  union { float f; u32 u; } c; c.f = f;
  return (u16)((c.u + 0x7fffu + ((c.u >> 16) & 1u)) >> 16);
}

// Fused front-end: all four weight casts + x cast + RoPE table in ONE launch.
__global__ __launch_bounds__(256)
void prep_k(const float* __restrict__ x,  const float* __restrict__ Wq,
            const float* __restrict__ Wk, const float* __restrict__ Wv,
            const float* __restrict__ Wo, const int* __restrict__ pos,
            u16* __restrict__ xb,  u16* __restrict__ wqb, u16* __restrict__ wkb,
            u16* __restrict__ wvb, u16* __restrict__ wob, float2* __restrict__ tab) {
  const int NX4 = MTOT * DM / 4;   // 2097152
  const int NW4 = DM * DM / 4;     // 262144
  const int i = blockIdx.x * blockDim.x + threadIdx.x;
  int j = i;
  const float* src = nullptr; u16* dst = nullptr;
  if (j < NX4) { src = x; dst = xb; }
  else {
    j -= NX4;
    if (j < NW4) { src = Wq; dst = wqb; }
    else if (j < 2 * NW4) { src = Wk; dst = wkb; j -= NW4; }
    else if (j < 3 * NW4) { src = Wv; dst = wvb; j -= 2 * NW4; }
    else if (j < 4 * NW4) { src = Wo; dst = wob; j -= 3 * NW4; }
    else {
      j -= 4 * NW4;
      if (j < SEQ * 32) {
        const int s = j >> 5, jj = j & 31;
        const float p = (float)pos[s];
        const float fr = powf(10000.f, -(float)jj / 32.f);
        tab[j] = make_float2(cosf(p * fr), sinf(p * fr));
      }
      return;
    }
  }
  float4 v = reinterpret_cast<const float4*>(src)[j];
  ushort4 o;
  o.x = f2bf(v.x); o.y = f2bf(v.y); o.z = f2bf(v.z); o.w = f2bf(v.w);
  reinterpret_cast<ushort4*>(dst)[j] = o;
}

// C = A @ Bt^T.  A: [M,1024] bf16 row-major. Bt: [1024,1024] bf16 row-major ([N][K]).
// R19: R16/R17's proven structure (128x128 tile, 4 waves 2x2, BK=32, TRIPLE-
// buffered 48KB, counted vmcnt(8/4/0), raw s_barriers, (row>>1)&3 swizzle both
// sides, XCD-local grid) with ONE change: 32x32x16 MFMA instead of 16x16x32.
// Mechanism: 2.44e-4 vs 2.96e-4 cyc/FLOP on the matrix pipe (m119) and half the
// issue slots (8 vs 16 MFMA/K-step). Per wave: 2x2 sub-tiles of 32x32,
// acc[2][2] f32x16 (same 64 regs). Operand layout (row=lane&31, k=16*kk+8*hi)
// and C layout (col=lane&31 = B rows, row=(r&3)+8(r>>2)+4hi = A rows) are the
// attn-verified mappings. Frag-read bank check: group = 4(row&1)+slot^((row>>1)&3)
// bijective per 8 rows -> conflict-free.  (R18's 8-wave blocks REGRESSED:
// occupancy 29->21, 99->119us -- reverted.)
// EPI 0: fp32 -> outF. EPI 1: z=0/1 -> RoPE -> Qh/Kh; z=2 -> Vt.
// Q pre-scaled by 0.125*log2(e) so attention softmax runs in exp2 domain.
template<int EPI>
__global__ __launch_bounds__(256)
void gemm_bt(const u16* __restrict__ A,
             const u16* __restrict__ B0, const u16* __restrict__ B1, const u16* __restrict__ B2,
             float* __restrict__ outF,
             u16* __restrict__ Qh, u16* __restrict__ Kh, u16* __restrict__ Vt,
             const float2* __restrict__ tab) {
  const int K = DM, N = DM;
  const int NT = K / 32;           // 32 K-steps
  __shared__ u16 lsA[3][128 * 32];
  __shared__ u16 lsB[3][128 * 32];
  const int t = threadIdx.x;
  const int lane = t & 63;
  const int wid = t >> 6;
  const int wr = wid >> 1, wc = wid & 1;
  const int m0 = blockIdx.x * 128;   // x = m-tile (64) -> xcd = m%8
  const int n0 = blockIdx.y * 128;   // y = n-tile (8)
  const int z = blockIdx.z;
  const u16* Bt = (z == 0) ? B0 : (z == 1 ? B1 : B2);

  f32x16 acc[2][2] = {};

  const int l31 = lane & 31, hi = lane >> 5;

#define STG(bf, kt_)                                                                 \
  {                                                                                  \
    _Pragma("unroll")                                                                \
    for (int p = 0; p < 2; ++p) {                                                    \
      const int idx = p * 256 + t;                                                   \
      const int row = idx >> 2;                                                      \
      const int sg = ((idx & 3) ^ ((row >> 1) & 3)) * 8;                             \
      __builtin_amdgcn_global_load_lds(                                              \
          (const as1_u32*)(A + (size_t)(m0 + row) * K + (kt_) * 32 + sg),            \
          (as3_u32*)((char*)&lsA[bf][0] + idx * 16), 16, 0, 0);                      \
      __builtin_amdgcn_global_load_lds(                                              \
          (const as1_u32*)(Bt + (size_t)(n0 + row) * K + (kt_) * 32 + sg),           \
          (as3_u32*)((char*)&lsB[bf][0] + idx * 16), 16, 0, 0);                      \
    }                                                                                \
  }

  STG(0, 0)
  STG(1, 1)
  STG(2, 2)

  int c = 0;
  for (int kt = 0; kt < NT; ++kt) {
    const int rem = NT - 1 - kt;
    if (rem >= 2)      { asm volatile("s_waitcnt vmcnt(8)" ::: "memory"); }
    else if (rem == 1) { asm volatile("s_waitcnt vmcnt(4)" ::: "memory"); }
    else               { asm volatile("s_waitcnt vmcnt(0)" ::: "memory"); }
    __builtin_amdgcn_sched_barrier(0);
    __builtin_amdgcn_s_barrier();

    bf16x8 af[2][2], bfr[2][2];
#pragma unroll
    for (int mi = 0; mi < 2; ++mi)
#pragma unroll
      for (int kk = 0; kk < 2; ++kk) {
        const int r = wr * 64 + mi * 32 + l31;
        const int slot = kk * 2 + hi;
        af[mi][kk] = *(const bf16x8*)&lsA[c][r * 32 + (slot ^ ((r >> 1) & 3)) * 8];
      }
#pragma unroll
    for (int ni = 0; ni < 2; ++ni)
#pragma unroll
      for (int kk = 0; kk < 2; ++kk) {
        const int r = wc * 64 + ni * 32 + l31;
        const int slot = kk * 2 + hi;
        bfr[ni][kk] = *(const bf16x8*)&lsB[c][r * 32 + (slot ^ ((r >> 1) & 3)) * 8];
      }
#pragma unroll
    for (int mi = 0; mi < 2; ++mi)
#pragma unroll
      for (int ni = 0; ni < 2; ++ni) {
        acc[mi][ni] = __builtin_amdgcn_mfma_f32_32x32x16_bf16(af[mi][0], bfr[ni][0], acc[mi][ni], 0, 0, 0);
        acc[mi][ni] = __builtin_amdgcn_mfma_f32_32x32x16_bf16(af[mi][1], bfr[ni][1], acc[mi][ni], 0, 0, 0);
      }

    __builtin_amdgcn_s_barrier();            // all waves done reading buf c
    if (kt + 3 < NT) STG(c, kt + 3)          // refill just-freed buffer
    c = (c == 2) ? 0 : c + 1;
  }
#undef STG

  // epilogue: C layout col = lane&31 (= N), row = (r&3)+8*(r>>2)+4*hi (= M)
#pragma unroll
  for (int mi = 0; mi < 2; ++mi) {
#pragma unroll
    for (int ni = 0; ni < 2; ++ni) {
      const int gn = n0 + wc * 64 + ni * 32 + l31;
#pragma unroll
      for (int r = 0; r < 16; ++r) {
        const int gm = m0 + wr * 64 + mi * 32 + (r & 3) + 8 * (r >> 2) + 4 * hi;
        float v = acc[mi][ni][r];
        if (EPI == 0) {
          outF[(size_t)gm * N + gn] = v;
        } else {
          const int b = gm >> 11, s = gm & (SEQ - 1);
          const int h = (gn & 1023) >> 6, dd = gn & 63;
          if (z < 2) {
            float p = __shfl_xor(v, 1);
            const float2 cs = tab[(s << 5) + (dd >> 1)];
            float o = ((lane & 1) == 0) ? (v * cs.x - p * cs.y) : (p * cs.y + v * cs.x);
            if (z == 0) o *= 0.18033688011112042f;  // 0.125 * log2(e)
            u16* dst = z ? Kh : Qh;
            dst[((size_t)((b * NH + h) * SEQ + s) << 6) + dd] = f2bf(o);
          } else {
            Vt[((size_t)((b * NH + h) << 6) + dd) * SEQ + s] = f2bf(v);
          }
        }
      }
    }
  }
}

// Flash attention, causal, log2-domain softmax, SWAPPED-OPERAND 32x32x16 MFMA
// (in-register softmax) + block-shared LDS K/V staging via global_load_lds with
// XOR swizzle; 2-tile-deep staging, counted vmcnt(2/0), raw s_barriers.
// 8-wave blocks (512 thr) owning 256 q-rows; each staged K/V tile feeds 8 waves;
// 32KB LDS. Grid 512 = 64 bh x 8 ranks, heavy-first; bid%8 = bh%8 (XCD-local).
// (R17-measured: ~62us, best attn so far.)
__global__ __launch_bounds__(512)
void attn_k(const u16* __restrict__ Qh, const u16* __restrict__ Kh,
            const u16* __restrict__ Vt, u16* __restrict__ AO) {
  __shared__ u16 lsK[2][64 * 64];
  __shared__ u16 lsV[2][64 * 64];
  const int t = threadIdx.x, lane = t & 63, w = t >> 6;   // w in [0,8)
  const int hiL = lane >> 5;
  const int q31 = lane & 31;
  const int bid = blockIdx.x;
  const int bh = bid & 63, b = bh >> 4, h = bh & 15;
  const int chunk_blk = 7 - (bid >> 6);       // heavy-first, 256-row chunks
  const int qb_blk = chunk_blk * 256;
  const int tendB = (qb_blk + 255) >> 6;      // >= 3 always
  const int qbase = qb_blk + w * 32;          // this wave's 32 q-rows
  const int tendW = (qbase + 31) >> 6;
  const u16* Qp = Qh + (size_t)bh * SEQ * 64;
  const u16* Kp = Kh + (size_t)bh * SEQ * 64;
  const u16* Vp = Vt + (size_t)bh * 64 * SEQ;

  bf16x8 qa[4];
#pragma unroll
  for (int kc = 0; kc < 4; ++kc)
    qa[kc] = *(const bf16x8*)(Qp + (size_t)(qbase + q31) * 64 + kc * 16 + hiL * 8);

  f32x16 O0 = {}, O1 = {};
  float m = -1e30f, l = 0.f;

#define STAGE(bf, kt_)                                                                  \
  {                                                                                     \
    const int k0s = (kt_) * 64;                                                         \
    const int row = t >> 3;                                                             \
    const int cb = ((t & 7) << 4) ^ ((row & 7) << 4);                                   \
    __builtin_amdgcn_global_load_lds((const as1_u32*)(Kp + (size_t)(k0s + row) * 64 + (cb >> 1)), \
                                     (as3_u32*)((char*)&lsK[bf][0] + t * 16), 16, 0, 0); \
    __builtin_amdgcn_global_load_lds((const as1_u32*)(Vp + (size_t)row * SEQ + k0s + (cb >> 1)), \
                                     (as3_u32*)((char*)&lsV[bf][0] + t * 16), 16, 0, 0); \
  }

  STAGE(0, 0)
  STAGE(1, 1)

  for (int kt = 0; kt <= tendB; ++kt) {
    const int cur = kt & 1;
    const int rem = tendB - kt;
    if (rem >= 1) { asm volatile("s_waitcnt vmcnt(2)" ::: "memory"); }
    else          { asm volatile("s_waitcnt vmcnt(0)" ::: "memory"); }
    __builtin_amdgcn_sched_barrier(0);
    __builtin_amdgcn_s_barrier();

    if (kt <= tendW) {
      const int k0 = kt * 64;
      const int swz = (q31 & 7) << 4;

      f32x16 S0 = {}, S1 = {};
#pragma unroll
      for (int kc = 0; kc < 4; ++kc) {
        const int cb = (kc * 32 + hiL * 16) ^ swz;
        bf16x8 ka = *(const bf16x8*)&lsK[cur][q31 * 64 + (cb >> 1)];
        S0 = __builtin_amdgcn_mfma_f32_32x32x16_bf16(ka, qa[kc], S0, 0, 0, 0);
      }
#pragma unroll
      for (int kc = 0; kc < 4; ++kc) {
        const int cb = (kc * 32 + hiL * 16) ^ swz;
        bf16x8 ka = *(const bf16x8*)&lsK[cur][(32 + q31) * 64 + (cb >> 1)];
        S1 = __builtin_amdgcn_mfma_f32_32x32x16_bf16(ka, qa[kc], S1, 0, 0, 0);
      }

      if (kt == tendW) {
        const int qg = qbase + q31;
#pragma unroll
        for (int r = 0; r < 16; ++r) {
          const int kg = k0 + (r & 3) + 8 * (r >> 2) + 4 * hiL;
          S0[r] = (kg > qg) ? -1e30f : S0[r];
          S1[r] = (kg + 32 > qg) ? -1e30f : S1[r];
        }
      }

      float vmax = -1e30f;
#pragma unroll
      for (int r = 0; r < 16; ++r) {
        vmax = fmaxf(vmax, S0[r]);
        vmax = fmaxf(vmax, S1[r]);
      }
      vmax = fmaxf(vmax, __shfl_xor(vmax, 32));

      if (vmax > m + 7.f) {    // defer-max (T13), log2 domain
        const float al = exp2f(m - vmax);
        m = vmax; l *= al;
#pragma unroll
        for (int r = 0; r < 16; ++r) { O0[r] *= al; O1[r] *= al; }
      }

      float rs = 0.f;
#pragma unroll
      for (int r = 0; r < 16; ++r) {
        const float p0 = exp2f(S0[r] - m);
        const float p1 = exp2f(S1[r] - m);
        S0[r] = p0; S1[r] = p1;
        rs += p0 + p1;
      }
      l += rs;

      bf16x8 pb[4];
#define PACKKC(SV, kb, OUT)                                                         \
      {                                                                             \
        u32 qL0, qL1, qH0, qH1;                                                     \
        asm("v_cvt_pk_bf16_f32 %0, %1, %2" : "=v"(qL0) : "v"(SV[8*(kb)+0]), "v"(SV[8*(kb)+1])); \
        asm("v_cvt_pk_bf16_f32 %0, %1, %2" : "=v"(qL1) : "v"(SV[8*(kb)+2]), "v"(SV[8*(kb)+3])); \
        asm("v_cvt_pk_bf16_f32 %0, %1, %2" : "=v"(qH0) : "v"(SV[8*(kb)+4]), "v"(SV[8*(kb)+5])); \
        asm("v_cvt_pk_bf16_f32 %0, %1, %2" : "=v"(qH1) : "v"(SV[8*(kb)+6]), "v"(SV[8*(kb)+7])); \
        const u32 sA = hiL ? qL0 : qH0;                                             \
        const u32 sB = hiL ? qL1 : qH1;                                             \
        const u32 rA = (u32)__shfl_xor((int)sA, 32);                                \
        const u32 rB = (u32)__shfl_xor((int)sB, 32);                                \
        union { u32 wds[4]; bf16x8 v; } uu;                                         \
        uu.wds[0] = hiL ? rA : qL0;                                                 \
        uu.wds[1] = hiL ? rB : qL1;                                                 \
        uu.wds[2] = hiL ? qH0 : rA;                                                 \
        uu.wds[3] = hiL ? qH1 : rB;                                                 \
        OUT = uu.v;                                                                 \
      }
      PACKKC(S0, 0, pb[0])
      PACKKC(S0, 1, pb[1])
      PACKKC(S1, 0, pb[2])
      PACKKC(S1, 1, pb[3])
#undef PACKKC

#pragma unroll
      for (int kc = 0; kc < 4; ++kc) {
        const int cb = (kc * 32 + hiL * 16) ^ swz;
        bf16x8 va0 = *(const bf16x8*)&lsV[cur][q31 * 64 + (cb >> 1)];
        bf16x8 va1 = *(const bf16x8*)&lsV[cur][(32 + q31) * 64 + (cb >> 1)];
        O0 = __builtin_amdgcn_mfma_f32_32x32x16_bf16(va0, pb[kc], O0, 0, 0, 0);
        O1 = __builtin_amdgcn_mfma_f32_32x32x16_bf16(va1, pb[kc], O1, 0, 0, 0);
      }
    }

    __builtin_amdgcn_s_barrier();            // all waves done reading buf cur
    if (kt + 2 <= tendB) STAGE(cur, kt + 2)  // overwrite now safe; 2 tiles to land
  }

  l += __shfl_xor(l, 32);
  const float inv = 1.f / l;
  const int s = qbase + q31;
  u16* dst = AO + ((size_t)(b * SEQ + s) * NH + h) * 64;
#pragma unroll
  for (int rp = 0; rp < 8; ++rp) {
    const int r = rp * 2;
    const int d = (r & 3) + 8 * (r >> 2) + 4 * hiL;
    u32 w0, w1;
    asm("v_cvt_pk_bf16_f32 %0, %1, %2" : "=v"(w0) : "v"(O0[r] * inv), "v"(O0[r + 1] * inv));
    asm("v_cvt_pk_bf16_f32 %0, %1, %2" : "=v"(w1) : "v"(O1[r] * inv), "v"(O1[r + 1] * inv));
    *reinterpret_cast<u32*>(dst + d) = w0;
    *reinterpret_cast<u32*>(dst + 32 + d) = w1;
  }
}

extern "C" void kernel_launch(void* const* d_in, const int* in_sizes, int n_in,
                              void* d_out, int out_size, void* d_ws, size_t ws_size,
                              hipStream_t stream) {
  const float* x  = (const float*)d_in[0];
  const int*   pos = (const int*)d_in[1];
  const float* Wq = (const float*)d_in[2];
  const float* Wk = (const float*)d_in[3];
  const float* Wv = (const float*)d_in[4];
  const float* Wo = (const float*)d_in[5];
  float* out = (float*)d_out;
  char* ws = (char*)d_ws;
  const size_t MB = 1024 * 1024;
  if (ws_size < 73 * MB) return;  // refuse to scribble OOB

  u16* xb  = (u16*)(ws);             // 16MB; re-used as AO after QKV proj
  u16* wqb = (u16*)(ws + 16 * MB);
  u16* wkb = (u16*)(ws + 18 * MB);
  u16* wvb = (u16*)(ws + 20 * MB);
  u16* wob = (u16*)(ws + 22 * MB);
  u16* Qh  = (u16*)(ws + 24 * MB);
  u16* Kh  = (u16*)(ws + 40 * MB);
  u16* Vt  = (u16*)(ws + 56 * MB);
  float2* tab = (float2*)(ws + 72 * MB);
  u16* AO = xb;

  const int NPREP = MTOT * DM / 4 + 4 * (DM * DM / 4) + SEQ * 32;
  prep_k<<<(NPREP + 255) / 256, 256, 0, stream>>>(x, Wq, Wk, Wv, Wo, pos,
                                                  xb, wqb, wkb, wvb, wob, tab);
  // grid: x = m-tile (64), y = n-tile (8), z = matrix -> xcd = m%8 (A-panel local)
  gemm_bt<1><<<dim3(64, 8, 3), 256, 0, stream>>>(xb, wqb, wkb, wvb, nullptr, Qh, Kh, Vt, tab);
  attn_k<<<dim3(512), 512, 0, stream>>>(Qh, Kh, Vt, AO);
  gemm_bt<0><<<dim3(64, 8, 1), 256, 0, stream>>>(AO, wob, wob, wob, out, nullptr, nullptr, nullptr, nullptr);
}

// Round 20
// 204.305 us; speedup vs baseline: 1.1466x; 1.1466x over previous
//
#include <hip/hip_runtime.h>

#define SEQ   2048
#define BATCH 4
#define NH    16
#define DM    1024
#define MTOT  (BATCH*SEQ)   // 8192

typedef unsigned short u16;
typedef unsigned int   u32;
typedef __attribute__((ext_vector_type(8)))  __bf16 bf16x8;
typedef __attribute__((ext_vector_type(4)))  float  f32x4;
typedef __attribute__((ext_vector_type(16))) float  f32x16;
typedef __attribute__((address_space(1))) u32 as1_u32;
typedef __attribute__((address_space(3))) u32 as3_u32;

__device__ __forceinline__ u16 f2bf(float f) {
  union { float f; u32 u; } c; c.f = f;
  return (u16)((c.u + 0x7fffu + ((c.u >> 16) & 1u)) >> 16);
}

// Fused front-end: all four weight casts + x cast + RoPE table in ONE launch.
__global__ __launch_bounds__(256)
void prep_k(const float* __restrict__ x,  const float* __restrict__ Wq,
            const float* __restrict__ Wk, const float* __restrict__ Wv,
            const float* __restrict__ Wo, const int* __restrict__ pos,
            u16* __restrict__ xb,  u16* __restrict__ wqb, u16* __restrict__ wkb,
            u16* __restrict__ wvb, u16* __restrict__ wob, float2* __restrict__ tab) {
  const int NX4 = MTOT * DM / 4;   // 2097152
  const int NW4 = DM * DM / 4;     // 262144
  const int i = blockIdx.x * blockDim.x + threadIdx.x;
  int j = i;
  const float* src = nullptr; u16* dst = nullptr;
  if (j < NX4) { src = x; dst = xb; }
  else {
    j -= NX4;
    if (j < NW4) { src = Wq; dst = wqb; }
    else if (j < 2 * NW4) { src = Wk; dst = wkb; j -= NW4; }
    else if (j < 3 * NW4) { src = Wv; dst = wvb; j -= 2 * NW4; }
    else if (j < 4 * NW4) { src = Wo; dst = wob; j -= 3 * NW4; }
    else {
      j -= 4 * NW4;
      if (j < SEQ * 32) {
        const int s = j >> 5, jj = j & 31;
        const float p = (float)pos[s];
        const float fr = powf(10000.f, -(float)jj / 32.f);
        tab[j] = make_float2(cosf(p * fr), sinf(p * fr));
      }
      return;
    }
  }
  float4 v = reinterpret_cast<const float4*>(src)[j];
  ushort4 o;
  o.x = f2bf(v.x); o.y = f2bf(v.y); o.z = f2bf(v.z); o.w = f2bf(v.w);
  reinterpret_cast<ushort4*>(dst)[j] = o;
}

// C = A @ Bt^T.  A: [M,1024] bf16 row-major. Bt: [1024,1024] bf16 row-major ([N][K]).
// R17-VERIFIED BEST config (99us, 520 TF, conflicts 0, VGPR 80, occ 29%):
// 128x128 tile, 4 waves 2x2, BK=32, TRIPLE-buffered 48KB, counted vmcnt(8/4/0)
// by remaining tiles, raw s_barriers, 16x16x32 MFMA, swizzle slot^((row>>1)&3)
// BOTH sides, grid (64 m,8 n,z): xcd=m%8 A-panel-local. Exhausted alternatives
// (all measured WORSE): depth-3 null (R16), BK=64 -10% (R14), 8-wave -20% (R18),
// 32x32 MFMA -30% + conflicts return (R19: swizzle is co-designed with the
// 16-row fragment read geometry), 8-phase 256^2 -18% grid-granularity (R9).
// EPI 0: fp32 -> outF. EPI 1: z=0/1 -> RoPE -> Qh/Kh; z=2 -> Vt.
// Q pre-scaled by 0.125*log2(e) so attention softmax runs in exp2 domain.
template<int EPI>
__global__ __launch_bounds__(256)
void gemm_bt(const u16* __restrict__ A,
             const u16* __restrict__ B0, const u16* __restrict__ B1, const u16* __restrict__ B2,
             float* __restrict__ outF,
             u16* __restrict__ Qh, u16* __restrict__ Kh, u16* __restrict__ Vt,
             const float2* __restrict__ tab) {
  const int K = DM, N = DM;
  const int NT = K / 32;           // 32 K-steps
  __shared__ u16 lsA[3][128 * 32];
  __shared__ u16 lsB[3][128 * 32];
  const int t = threadIdx.x;
  const int lane = t & 63;
  const int wid = t >> 6;
  const int wr = wid >> 1, wc = wid & 1;
  const int m0 = blockIdx.x * 128;   // x = m-tile (64) -> xcd = m%8
  const int n0 = blockIdx.y * 128;   // y = n-tile (8)
  const int z = blockIdx.z;
  const u16* Bt = (z == 0) ? B0 : (z == 1 ? B1 : B2);

  f32x4 acc[4][4] = {};

  const int l15 = lane & 15, lsl = lane >> 4;

#define STG(bf, kt_)                                                                 \
  {                                                                                  \
    _Pragma("unroll")                                                                \
    for (int p = 0; p < 2; ++p) {                                                    \
      const int idx = p * 256 + t;                                                   \
      const int row = idx >> 2;                                                      \
      const int sg = ((idx & 3) ^ ((row >> 1) & 3)) * 8;                             \
      __builtin_amdgcn_global_load_lds(                                              \
          (const as1_u32*)(A + (size_t)(m0 + row) * K + (kt_) * 32 + sg),            \
          (as3_u32*)((char*)&lsA[bf][0] + idx * 16), 16, 0, 0);                      \
      __builtin_amdgcn_global_load_lds(                                              \
          (const as1_u32*)(Bt + (size_t)(n0 + row) * K + (kt_) * 32 + sg),           \
          (as3_u32*)((char*)&lsB[bf][0] + idx * 16), 16, 0, 0);                      \
    }                                                                                \
  }

  STG(0, 0)
  STG(1, 1)
  STG(2, 2)

  int c = 0;
  for (int kt = 0; kt < NT; ++kt) {
    const int rem = NT - 1 - kt;
    if (rem >= 2)      { asm volatile("s_waitcnt vmcnt(8)" ::: "memory"); }
    else if (rem == 1) { asm volatile("s_waitcnt vmcnt(4)" ::: "memory"); }
    else               { asm volatile("s_waitcnt vmcnt(0)" ::: "memory"); }
    __builtin_amdgcn_sched_barrier(0);
    __builtin_amdgcn_s_barrier();

    bf16x8 af[4], bfr[4];
#pragma unroll
    for (int mt = 0; mt < 4; ++mt) {
      const int r = wr * 64 + mt * 16 + l15;
      af[mt] = *(const bf16x8*)&lsA[c][r * 32 + (lsl ^ ((r >> 1) & 3)) * 8];
    }
#pragma unroll
    for (int nt = 0; nt < 4; ++nt) {
      const int r = wc * 64 + nt * 16 + l15;
      bfr[nt] = *(const bf16x8*)&lsB[c][r * 32 + (lsl ^ ((r >> 1) & 3)) * 8];
    }
#pragma unroll
    for (int mt = 0; mt < 4; ++mt)
#pragma unroll
      for (int nt = 0; nt < 4; ++nt)
        acc[mt][nt] = __builtin_amdgcn_mfma_f32_16x16x32_bf16(af[mt], bfr[nt], acc[mt][nt], 0, 0, 0);

    __builtin_amdgcn_s_barrier();            // all waves done reading buf c
    if (kt + 3 < NT) STG(c, kt + 3)          // refill just-freed buffer
    c = (c == 2) ? 0 : c + 1;
  }
#undef STG

#pragma unroll
  for (int mt = 0; mt < 4; ++mt) {
    const int gmb = m0 + wr * 64 + mt * 16 + (lane >> 4) * 4;
#pragma unroll
    for (int nt = 0; nt < 4; ++nt) {
      const int gn = n0 + wc * 64 + nt * 16 + (lane & 15);
#pragma unroll
      for (int r = 0; r < 4; ++r) {
        float v = acc[mt][nt][r];
        if (EPI == 0) {
          outF[(size_t)(gmb + r) * N + gn] = v;
        } else {
          const int row = gmb + r;
          const int b = row >> 11, s = row & (SEQ - 1);
          const int h = gn >> 6, dd = gn & 63;
          if (z < 2) {
            float p = __shfl_xor(v, 1);
            const float2 cs = tab[(s << 5) + (dd >> 1)];
            float o = ((lane & 1) == 0) ? (v * cs.x - p * cs.y) : (p * cs.y + v * cs.x);
            if (z == 0) o *= 0.18033688011112042f;  // 0.125 * log2(e)
            u16* dst = z ? Kh : Qh;
            dst[((size_t)((b * NH + h) * SEQ + s) << 6) + dd] = f2bf(o);
          } else {
            Vt[((size_t)((b * NH + h) << 6) + dd) * SEQ + s] = f2bf(v);
          }
        }
      }
    }
  }
}

// Flash attention, causal, log2-domain softmax, SWAPPED-OPERAND 32x32x16 MFMA
// (in-register softmax) + block-shared LDS K/V staging via global_load_lds with
// XOR swizzle; 2-tile-deep staging, counted vmcnt(2/0), raw s_barriers.
// 8-wave blocks (512 thr) owning 256 q-rows; 32KB LDS; grid 512 = 64 bh x 8
// ranks, heavy-first; bid%8 = bh%8 (XCD-local). R17-measured ~62us.
// R20: + T5 s_setprio(1) around the MFMA clusters (QK and PV) -- attn's 8
// waves have phase diversity (diagonal-dependent work + staggered stages), the
// precondition under which learn_hip measured +4-7% (m191); GEMM lockstep got
// null (m190), so setprio is applied HERE only.
__global__ __launch_bounds__(512)
void attn_k(const u16* __restrict__ Qh, const u16* __restrict__ Kh,
            const u16* __restrict__ Vt, u16* __restrict__ AO) {
  __shared__ u16 lsK[2][64 * 64];
  __shared__ u16 lsV[2][64 * 64];
  const int t = threadIdx.x, lane = t & 63, w = t >> 6;   // w in [0,8)
  const int hiL = lane >> 5;
  const int q31 = lane & 31;
  const int bid = blockIdx.x;
  const int bh = bid & 63, b = bh >> 4, h = bh & 15;
  const int chunk_blk = 7 - (bid >> 6);       // heavy-first, 256-row chunks
  const int qb_blk = chunk_blk * 256;
  const int tendB = (qb_blk + 255) >> 6;      // >= 3 always
  const int qbase = qb_blk + w * 32;          // this wave's 32 q-rows
  const int tendW = (qbase + 31) >> 6;
  const u16* Qp = Qh + (size_t)bh * SEQ * 64;
  const u16* Kp = Kh + (size_t)bh * SEQ * 64;
  const u16* Vp = Vt + (size_t)bh * 64 * SEQ;

  bf16x8 qa[4];
#pragma unroll
  for (int kc = 0; kc < 4; ++kc)
    qa[kc] = *(const bf16x8*)(Qp + (size_t)(qbase + q31) * 64 + kc * 16 + hiL * 8);

  f32x16 O0 = {}, O1 = {};
  float m = -1e30f, l = 0.f;

#define STAGE(bf, kt_)                                                                  \
  {                                                                                     \
    const int k0s = (kt_) * 64;                                                         \
    const int row = t >> 3;                                                             \
    const int cb = ((t & 7) << 4) ^ ((row & 7) << 4);                                   \
    __builtin_amdgcn_global_load_lds((const as1_u32*)(Kp + (size_t)(k0s + row) * 64 + (cb >> 1)), \
                                     (as3_u32*)((char*)&lsK[bf][0] + t * 16), 16, 0, 0); \
    __builtin_amdgcn_global_load_lds((const as1_u32*)(Vp + (size_t)row * SEQ + k0s + (cb >> 1)), \
                                     (as3_u32*)((char*)&lsV[bf][0] + t * 16), 16, 0, 0); \
  }

  STAGE(0, 0)
  STAGE(1, 1)

  for (int kt = 0; kt <= tendB; ++kt) {
    const int cur = kt & 1;
    const int rem = tendB - kt;
    if (rem >= 1) { asm volatile("s_waitcnt vmcnt(2)" ::: "memory"); }
    else          { asm volatile("s_waitcnt vmcnt(0)" ::: "memory"); }
    __builtin_amdgcn_sched_barrier(0);
    __builtin_amdgcn_s_barrier();

    if (kt <= tendW) {
      const int k0 = kt * 64;
      const int swz = (q31 & 7) << 4;

      f32x16 S0 = {}, S1 = {};
      __builtin_amdgcn_s_setprio(1);
#pragma unroll
      for (int kc = 0; kc < 4; ++kc) {
        const int cb = (kc * 32 + hiL * 16) ^ swz;
        bf16x8 ka = *(const bf16x8*)&lsK[cur][q31 * 64 + (cb >> 1)];
        S0 = __builtin_amdgcn_mfma_f32_32x32x16_bf16(ka, qa[kc], S0, 0, 0, 0);
      }
#pragma unroll
      for (int kc = 0; kc < 4; ++kc) {
        const int cb = (kc * 32 + hiL * 16) ^ swz;
        bf16x8 ka = *(const bf16x8*)&lsK[cur][(32 + q31) * 64 + (cb >> 1)];
        S1 = __builtin_amdgcn_mfma_f32_32x32x16_bf16(ka, qa[kc], S1, 0, 0, 0);
      }
      __builtin_amdgcn_s_setprio(0);

      if (kt == tendW) {
        const int qg = qbase + q31;
#pragma unroll
        for (int r = 0; r < 16; ++r) {
          const int kg = k0 + (r & 3) + 8 * (r >> 2) + 4 * hiL;
          S0[r] = (kg > qg) ? -1e30f : S0[r];
          S1[r] = (kg + 32 > qg) ? -1e30f : S1[r];
        }
      }

      float vmax = -1e30f;
#pragma unroll
      for (int r = 0; r < 16; ++r) {
        vmax = fmaxf(vmax, S0[r]);
        vmax = fmaxf(vmax, S1[r]);
      }
      vmax = fmaxf(vmax, __shfl_xor(vmax, 32));

      if (vmax > m + 7.f) {    // defer-max (T13), log2 domain
        const float al = exp2f(m - vmax);
        m = vmax; l *= al;
#pragma unroll
        for (int r = 0; r < 16; ++r) { O0[r] *= al; O1[r] *= al; }
      }

      float rs = 0.f;
#pragma unroll
      for (int r = 0; r < 16; ++r) {
        const float p0 = exp2f(S0[r] - m);
        const float p1 = exp2f(S1[r] - m);
        S0[r] = p0; S1[r] = p1;
        rs += p0 + p1;
      }
      l += rs;

      bf16x8 pb[4];
#define PACKKC(SV, kb, OUT)                                                         \
      {                                                                             \
        u32 qL0, qL1, qH0, qH1;                                                     \
        asm("v_cvt_pk_bf16_f32 %0, %1, %2" : "=v"(qL0) : "v"(SV[8*(kb)+0]), "v"(SV[8*(kb)+1])); \
        asm("v_cvt_pk_bf16_f32 %0, %1, %2" : "=v"(qL1) : "v"(SV[8*(kb)+2]), "v"(SV[8*(kb)+3])); \
        asm("v_cvt_pk_bf16_f32 %0, %1, %2" : "=v"(qH0) : "v"(SV[8*(kb)+4]), "v"(SV[8*(kb)+5])); \
        asm("v_cvt_pk_bf16_f32 %0, %1, %2" : "=v"(qH1) : "v"(SV[8*(kb)+6]), "v"(SV[8*(kb)+7])); \
        const u32 sA = hiL ? qL0 : qH0;                                             \
        const u32 sB = hiL ? qL1 : qH1;                                             \
        const u32 rA = (u32)__shfl_xor((int)sA, 32);                                \
        const u32 rB = (u32)__shfl_xor((int)sB, 32);                                \
        union { u32 wds[4]; bf16x8 v; } uu;                                         \
        uu.wds[0] = hiL ? rA : qL0;                                                 \
        uu.wds[1] = hiL ? rB : qL1;                                                 \
        uu.wds[2] = hiL ? qH0 : rA;                                                 \
        uu.wds[3] = hiL ? qH1 : rB;                                                 \
        OUT = uu.v;                                                                 \
      }
      PACKKC(S0, 0, pb[0])
      PACKKC(S0, 1, pb[1])
      PACKKC(S1, 0, pb[2])
      PACKKC(S1, 1, pb[3])
#undef PACKKC

      __builtin_amdgcn_s_setprio(1);
#pragma unroll
      for (int kc = 0; kc < 4; ++kc) {
        const int cb = (kc * 32 + hiL * 16) ^ swz;
        bf16x8 va0 = *(const bf16x8*)&lsV[cur][q31 * 64 + (cb >> 1)];
        bf16x8 va1 = *(const bf16x8*)&lsV[cur][(32 + q31) * 64 + (cb >> 1)];
        O0 = __builtin_amdgcn_mfma_f32_32x32x16_bf16(va0, pb[kc], O0, 0, 0, 0);
        O1 = __builtin_amdgcn_mfma_f32_32x32x16_bf16(va1, pb[kc], O1, 0, 0, 0);
      }
      __builtin_amdgcn_s_setprio(0);
    }

    __builtin_amdgcn_s_barrier();            // all waves done reading buf cur
    if (kt + 2 <= tendB) STAGE(cur, kt + 2)  // overwrite now safe; 2 tiles to land
  }

  l += __shfl_xor(l, 32);
  const float inv = 1.f / l;
  const int s = qbase + q31;
  u16* dst = AO + ((size_t)(b * SEQ + s) * NH + h) * 64;
#pragma unroll
  for (int rp = 0; rp < 8; ++rp) {
    const int r = rp * 2;
    const int d = (r & 3) + 8 * (r >> 2) + 4 * hiL;
    u32 w0, w1;
    asm("v_cvt_pk_bf16_f32 %0, %1, %2" : "=v"(w0) : "v"(O0[r] * inv), "v"(O0[r + 1] * inv));
    asm("v_cvt_pk_bf16_f32 %0, %1, %2" : "=v"(w1) : "v"(O1[r] * inv), "v"(O1[r + 1] * inv));
    *reinterpret_cast<u32*>(dst + d) = w0;
    *reinterpret_cast<u32*>(dst + 32 + d) = w1;
  }
}

extern "C" void kernel_launch(void* const* d_in, const int* in_sizes, int n_in,
                              void* d_out, int out_size, void* d_ws, size_t ws_size,
                              hipStream_t stream) {
  const float* x  = (const float*)d_in[0];
  const int*   pos = (const int*)d_in[1];
  const float* Wq = (const float*)d_in[2];
  const float* Wk = (const float*)d_in[3];
  const float* Wv = (const float*)d_in[4];
  const float* Wo = (const float*)d_in[5];
  float* out = (float*)d_out;
  char* ws = (char*)d_ws;
  const size_t MB = 1024 * 1024;
  if (ws_size < 73 * MB) return;  // refuse to scribble OOB

  u16* xb  = (u16*)(ws);             // 16MB; re-used as AO after QKV proj
  u16* wqb = (u16*)(ws + 16 * MB);
  u16* wkb = (u16*)(ws + 18 * MB);
  u16* wvb = (u16*)(ws + 20 * MB);
  u16* wob = (u16*)(ws + 22 * MB);
  u16* Qh  = (u16*)(ws + 24 * MB);
  u16* Kh  = (u16*)(ws + 40 * MB);
  u16* Vt  = (u16*)(ws + 56 * MB);
  float2* tab = (float2*)(ws + 72 * MB);
  u16* AO = xb;

  const int NPREP = MTOT * DM / 4 + 4 * (DM * DM / 4) + SEQ * 32;
  prep_k<<<(NPREP + 255) / 256, 256, 0, stream>>>(x, Wq, Wk, Wv, Wo, pos,
                                                  xb, wqb, wkb, wvb, wob, tab);
  // grid: x = m-tile (64), y = n-tile (8), z = matrix -> xcd = m%8 (A-panel local)
  gemm_bt<1><<<dim3(64, 8, 3), 256, 0, stream>>>(xb, wqb, wkb, wvb, nullptr, Qh, Kh, Vt, tab);
  attn_k<<<dim3(512), 512, 0, stream>>>(Qh, Kh, Vt, AO);
  gemm_bt<0><<<dim3(64, 8, 1), 256, 0, stream>>>(AO, wob, wob, wob, out, nullptr, nullptr, nullptr, nullptr);
}

// Round 21
// 203.911 us; speedup vs baseline: 1.1489x; 1.0019x over previous
//
#include <hip/hip_runtime.h>

#define SEQ   2048
#define BATCH 4
#define NH    16
#define DM    1024
#define MTOT  (BATCH*SEQ)   // 8192

typedef unsigned short u16;
typedef unsigned int   u32;
typedef __attribute__((ext_vector_type(8)))  __bf16 bf16x8;
typedef __attribute__((ext_vector_type(4)))  float  f32x4;
typedef __attribute__((ext_vector_type(16))) float  f32x16;
typedef __attribute__((address_space(1))) u32 as1_u32;
typedef __attribute__((address_space(3))) u32 as3_u32;

__device__ __forceinline__ u16 f2bf(float f) {
  union { float f; u32 u; } c; c.f = f;
  return (u16)((c.u + 0x7fffu + ((c.u >> 16) & 1u)) >> 16);
}

// Fused front-end: all four weight casts + x cast + RoPE table in ONE launch.
// (~12us at ~5 TB/s effective -- HBM-bound, at ceiling.)
__global__ __launch_bounds__(256)
void prep_k(const float* __restrict__ x,  const float* __restrict__ Wq,
            const float* __restrict__ Wk, const float* __restrict__ Wv,
            const float* __restrict__ Wo, const int* __restrict__ pos,
            u16* __restrict__ xb,  u16* __restrict__ wqb, u16* __restrict__ wkb,
            u16* __restrict__ wvb, u16* __restrict__ wob, float2* __restrict__ tab) {
  const int NX4 = MTOT * DM / 4;   // 2097152
  const int NW4 = DM * DM / 4;     // 262144
  const int i = blockIdx.x * blockDim.x + threadIdx.x;
  int j = i;
  const float* src = nullptr; u16* dst = nullptr;
  if (j < NX4) { src = x; dst = xb; }
  else {
    j -= NX4;
    if (j < NW4) { src = Wq; dst = wqb; }
    else if (j < 2 * NW4) { src = Wk; dst = wkb; j -= NW4; }
    else if (j < 3 * NW4) { src = Wv; dst = wvb; j -= 2 * NW4; }
    else if (j < 4 * NW4) { src = Wo; dst = wob; j -= 3 * NW4; }
    else {
      j -= 4 * NW4;
      if (j < SEQ * 32) {
        const int s = j >> 5, jj = j & 31;
        const float p = (float)pos[s];
        const float fr = powf(10000.f, -(float)jj / 32.f);
        tab[j] = make_float2(cosf(p * fr), sinf(p * fr));
      }
      return;
    }
  }
  float4 v = reinterpret_cast<const float4*>(src)[j];
  ushort4 o;
  o.x = f2bf(v.x); o.y = f2bf(v.y); o.z = f2bf(v.z); o.w = f2bf(v.w);
  reinterpret_cast<ushort4*>(dst)[j] = o;
}

// C = A @ Bt^T.  A: [M,1024] bf16 row-major. Bt: [1024,1024] bf16 row-major ([N][K]).
// R17-VERIFIED BEST config (98.5us, 523 TF, conflicts 0, VGPR 80, occ 29%):
// 128x128 tile, 4 waves 2x2, BK=32, TRIPLE-buffered 48KB, counted vmcnt(8/4/0)
// by remaining tiles, raw s_barriers, 16x16x32 MFMA, swizzle slot^((row>>1)&3)
// BOTH sides, grid (64 m,8 n,z): xcd=m%8 A-panel-local. Exhausted alternatives
// (all measured WORSE): depth-3 null (R16), BK=64 -10% (R14), 8-wave -20% (R18),
// 32x32 MFMA -30% + conflicts return (R19), 8-phase 256^2 -18% (R9 grid
// granularity), setprio null (R20/m190 lockstep).
// EPI 0: fp32 -> outF. EPI 1: z=0/1 -> RoPE -> Qh/Kh; z=2 -> Vt.
// Q pre-scaled by 0.125*log2(e) so attention softmax runs in exp2 domain.
template<int EPI>
__global__ __launch_bounds__(256)
void gemm_bt(const u16* __restrict__ A,
             const u16* __restrict__ B0, const u16* __restrict__ B1, const u16* __restrict__ B2,
             float* __restrict__ outF,
             u16* __restrict__ Qh, u16* __restrict__ Kh, u16* __restrict__ Vt,
             const float2* __restrict__ tab) {
  const int K = DM, N = DM;
  const int NT = K / 32;           // 32 K-steps
  __shared__ u16 lsA[3][128 * 32];
  __shared__ u16 lsB[3][128 * 32];
  const int t = threadIdx.x;
  const int lane = t & 63;
  const int wid = t >> 6;
  const int wr = wid >> 1, wc = wid & 1;
  const int m0 = blockIdx.x * 128;   // x = m-tile (64) -> xcd = m%8
  const int n0 = blockIdx.y * 128;   // y = n-tile (8)
  const int z = blockIdx.z;
  const u16* Bt = (z == 0) ? B0 : (z == 1 ? B1 : B2);

  f32x4 acc[4][4] = {};

  const int l15 = lane & 15, lsl = lane >> 4;

#define STG(bf, kt_)                                                                 \
  {                                                                                  \
    _Pragma("unroll")                                                                \
    for (int p = 0; p < 2; ++p) {                                                    \
      const int idx = p * 256 + t;                                                   \
      const int row = idx >> 2;                                                      \
      const int sg = ((idx & 3) ^ ((row >> 1) & 3)) * 8;                             \
      __builtin_amdgcn_global_load_lds(                                              \
          (const as1_u32*)(A + (size_t)(m0 + row) * K + (kt_) * 32 + sg),            \
          (as3_u32*)((char*)&lsA[bf][0] + idx * 16), 16, 0, 0);                      \
      __builtin_amdgcn_global_load_lds(                                              \
          (const as1_u32*)(Bt + (size_t)(n0 + row) * K + (kt_) * 32 + sg),           \
          (as3_u32*)((char*)&lsB[bf][0] + idx * 16), 16, 0, 0);                      \
    }                                                                                \
  }

  STG(0, 0)
  STG(1, 1)
  STG(2, 2)

  int c = 0;
  for (int kt = 0; kt < NT; ++kt) {
    const int rem = NT - 1 - kt;
    if (rem >= 2)      { asm volatile("s_waitcnt vmcnt(8)" ::: "memory"); }
    else if (rem == 1) { asm volatile("s_waitcnt vmcnt(4)" ::: "memory"); }
    else               { asm volatile("s_waitcnt vmcnt(0)" ::: "memory"); }
    __builtin_amdgcn_sched_barrier(0);
    __builtin_amdgcn_s_barrier();

    bf16x8 af[4], bfr[4];
#pragma unroll
    for (int mt = 0; mt < 4; ++mt) {
      const int r = wr * 64 + mt * 16 + l15;
      af[mt] = *(const bf16x8*)&lsA[c][r * 32 + (lsl ^ ((r >> 1) & 3)) * 8];
    }
#pragma unroll
    for (int nt = 0; nt < 4; ++nt) {
      const int r = wc * 64 + nt * 16 + l15;
      bfr[nt] = *(const bf16x8*)&lsB[c][r * 32 + (lsl ^ ((r >> 1) & 3)) * 8];
    }
#pragma unroll
    for (int mt = 0; mt < 4; ++mt)
#pragma unroll
      for (int nt = 0; nt < 4; ++nt)
        acc[mt][nt] = __builtin_amdgcn_mfma_f32_16x16x32_bf16(af[mt], bfr[nt], acc[mt][nt], 0, 0, 0);

    __builtin_amdgcn_s_barrier();            // all waves done reading buf c
    if (kt + 3 < NT) STG(c, kt + 3)          // refill just-freed buffer
    c = (c == 2) ? 0 : c + 1;
  }
#undef STG

#pragma unroll
  for (int mt = 0; mt < 4; ++mt) {
    const int gmb = m0 + wr * 64 + mt * 16 + (lane >> 4) * 4;
#pragma unroll
    for (int nt = 0; nt < 4; ++nt) {
      const int gn = n0 + wc * 64 + nt * 16 + (lane & 15);
#pragma unroll
      for (int r = 0; r < 4; ++r) {
        float v = acc[mt][nt][r];
        if (EPI == 0) {
          outF[(size_t)(gmb + r) * N + gn] = v;
        } else {
          const int row = gmb + r;
          const int b = row >> 11, s = row & (SEQ - 1);
          const int h = gn >> 6, dd = gn & 63;
          if (z < 2) {
            float p = __shfl_xor(v, 1);
            const float2 cs = tab[(s << 5) + (dd >> 1)];
            float o = ((lane & 1) == 0) ? (v * cs.x - p * cs.y) : (p * cs.y + v * cs.x);
            if (z == 0) o *= 0.18033688011112042f;  // 0.125 * log2(e)
            u16* dst = z ? Kh : Qh;
            dst[((size_t)((b * NH + h) * SEQ + s) << 6) + dd] = f2bf(o);
          } else {
            Vt[((size_t)((b * NH + h) << 6) + dd) * SEQ + s] = f2bf(v);
          }
        }
      }
    }
  }
}

// Flash attention, causal, log2-domain softmax, SWAPPED-OPERAND 32x32x16 MFMA
// (in-register softmax) + block-shared LDS K/V staging via global_load_lds with
// XOR swizzle; 2-tile-deep staging, counted vmcnt(2/0), raw s_barriers.
// 8-wave blocks (512 thr) owning 256 q-rows; 32KB LDS; grid 512 = 64 bh x 8
// ranks; bid%8 = bh%8 (XCD-local).
// R21: COMPLEMENTARY CHUNK PAIRING. 2 blocks co-reside per CU, and empirical
// round-robin dispatch puts bid and bid+256 on the same CU. Old mapping paired
// (32+16)=48 vs (20+4)=24 tile-units per CU -> makespan tracked the 48s while
// the 24s idled. New mapping: rank<4 -> chunk 7-rank (heavy-first), rank>=4 ->
// chunk rank-4, so every CU hosts chunks {7-x, x} = uniform 36 tile-units.
// Per-wave math unchanged. setprio kept (neutral, R20).
__global__ __launch_bounds__(512)
void attn_k(const u16* __restrict__ Qh, const u16* __restrict__ Kh,
            const u16* __restrict__ Vt, u16* __restrict__ AO) {
  __shared__ u16 lsK[2][64 * 64];
  __shared__ u16 lsV[2][64 * 64];
  const int t = threadIdx.x, lane = t & 63, w = t >> 6;   // w in [0,8)
  const int hiL = lane >> 5;
  const int q31 = lane & 31;
  const int bid = blockIdx.x;
  const int bh = bid & 63, b = bh >> 4, h = bh & 15;
  const int rank = bid >> 6;                  // [0,8)
  const int chunk_blk = (rank < 4) ? (7 - rank) : (rank - 4);  // complementary pairs
  const int qb_blk = chunk_blk * 256;
  const int tendB = (qb_blk + 255) >> 6;      // >= 3 always
  const int qbase = qb_blk + w * 32;          // this wave's 32 q-rows
  const int tendW = (qbase + 31) >> 6;
  const u16* Qp = Qh + (size_t)bh * SEQ * 64;
  const u16* Kp = Kh + (size_t)bh * SEQ * 64;
  const u16* Vp = Vt + (size_t)bh * 64 * SEQ;

  bf16x8 qa[4];
#pragma unroll
  for (int kc = 0; kc < 4; ++kc)
    qa[kc] = *(const bf16x8*)(Qp + (size_t)(qbase + q31) * 64 + kc * 16 + hiL * 8);

  f32x16 O0 = {}, O1 = {};
  float m = -1e30f, l = 0.f;

#define STAGE(bf, kt_)                                                                  \
  {                                                                                     \
    const int k0s = (kt_) * 64;                                                         \
    const int row = t >> 3;                                                             \
    const int cb = ((t & 7) << 4) ^ ((row & 7) << 4);                                   \
    __builtin_amdgcn_global_load_lds((const as1_u32*)(Kp + (size_t)(k0s + row) * 64 + (cb >> 1)), \
                                     (as3_u32*)((char*)&lsK[bf][0] + t * 16), 16, 0, 0); \
    __builtin_amdgcn_global_load_lds((const as1_u32*)(Vp + (size_t)row * SEQ + k0s + (cb >> 1)), \
                                     (as3_u32*)((char*)&lsV[bf][0] + t * 16), 16, 0, 0); \
  }

  STAGE(0, 0)
  STAGE(1, 1)

  for (int kt = 0; kt <= tendB; ++kt) {
    const int cur = kt & 1;
    const int rem = tendB - kt;
    if (rem >= 1) { asm volatile("s_waitcnt vmcnt(2)" ::: "memory"); }
    else          { asm volatile("s_waitcnt vmcnt(0)" ::: "memory"); }
    __builtin_amdgcn_sched_barrier(0);
    __builtin_amdgcn_s_barrier();

    if (kt <= tendW) {
      const int k0 = kt * 64;
      const int swz = (q31 & 7) << 4;

      f32x16 S0 = {}, S1 = {};
      __builtin_amdgcn_s_setprio(1);
#pragma unroll
      for (int kc = 0; kc < 4; ++kc) {
        const int cb = (kc * 32 + hiL * 16) ^ swz;
        bf16x8 ka = *(const bf16x8*)&lsK[cur][q31 * 64 + (cb >> 1)];
        S0 = __builtin_amdgcn_mfma_f32_32x32x16_bf16(ka, qa[kc], S0, 0, 0, 0);
      }
#pragma unroll
      for (int kc = 0; kc < 4; ++kc) {
        const int cb = (kc * 32 + hiL * 16) ^ swz;
        bf16x8 ka = *(const bf16x8*)&lsK[cur][(32 + q31) * 64 + (cb >> 1)];
        S1 = __builtin_amdgcn_mfma_f32_32x32x16_bf16(ka, qa[kc], S1, 0, 0, 0);
      }
      __builtin_amdgcn_s_setprio(0);

      if (kt == tendW) {
        const int qg = qbase + q31;
#pragma unroll
        for (int r = 0; r < 16; ++r) {
          const int kg = k0 + (r & 3) + 8 * (r >> 2) + 4 * hiL;
          S0[r] = (kg > qg) ? -1e30f : S0[r];
          S1[r] = (kg + 32 > qg) ? -1e30f : S1[r];
        }
      }

      float vmax = -1e30f;
#pragma unroll
      for (int r = 0; r < 16; ++r) {
        vmax = fmaxf(vmax, S0[r]);
        vmax = fmaxf(vmax, S1[r]);
      }
      vmax = fmaxf(vmax, __shfl_xor(vmax, 32));

      if (vmax > m + 7.f) {    // defer-max (T13), log2 domain
        const float al = exp2f(m - vmax);
        m = vmax; l *= al;
#pragma unroll
        for (int r = 0; r < 16; ++r) { O0[r] *= al; O1[r] *= al; }
      }

      float rs = 0.f;
#pragma unroll
      for (int r = 0; r < 16; ++r) {
        const float p0 = exp2f(S0[r] - m);
        const float p1 = exp2f(S1[r] - m);
        S0[r] = p0; S1[r] = p1;
        rs += p0 + p1;
      }
      l += rs;

      bf16x8 pb[4];
#define PACKKC(SV, kb, OUT)                                                         \
      {                                                                             \
        u32 qL0, qL1, qH0, qH1;                                                     \
        asm("v_cvt_pk_bf16_f32 %0, %1, %2" : "=v"(qL0) : "v"(SV[8*(kb)+0]), "v"(SV[8*(kb)+1])); \
        asm("v_cvt_pk_bf16_f32 %0, %1, %2" : "=v"(qL1) : "v"(SV[8*(kb)+2]), "v"(SV[8*(kb)+3])); \
        asm("v_cvt_pk_bf16_f32 %0, %1, %2" : "=v"(qH0) : "v"(SV[8*(kb)+4]), "v"(SV[8*(kb)+5])); \
        asm("v_cvt_pk_bf16_f32 %0, %1, %2" : "=v"(qH1) : "v"(SV[8*(kb)+6]), "v"(SV[8*(kb)+7])); \
        const u32 sA = hiL ? qL0 : qH0;                                             \
        const u32 sB = hiL ? qL1 : qH1;                                             \
        const u32 rA = (u32)__shfl_xor((int)sA, 32);                                \
        const u32 rB = (u32)__shfl_xor((int)sB, 32);                                \
        union { u32 wds[4]; bf16x8 v; } uu;                                         \
        uu.wds[0] = hiL ? rA : qL0;                                                 \
        uu.wds[1] = hiL ? rB : qL1;                                                 \
        uu.wds[2] = hiL ? qH0 : rA;                                                 \
        uu.wds[3] = hiL ? qH1 : rB;                                                 \
        OUT = uu.v;                                                                 \
      }
      PACKKC(S0, 0, pb[0])
      PACKKC(S0, 1, pb[1])
      PACKKC(S1, 0, pb[2])
      PACKKC(S1, 1, pb[3])
#undef PACKKC

      __builtin_amdgcn_s_setprio(1);
#pragma unroll
      for (int kc = 0; kc < 4; ++kc) {
        const int cb = (kc * 32 + hiL * 16) ^ swz;
        bf16x8 va0 = *(const bf16x8*)&lsV[cur][q31 * 64 + (cb >> 1)];
        bf16x8 va1 = *(const bf16x8*)&lsV[cur][(32 + q31) * 64 + (cb >> 1)];
        O0 = __builtin_amdgcn_mfma_f32_32x32x16_bf16(va0, pb[kc], O0, 0, 0, 0);
        O1 = __builtin_amdgcn_mfma_f32_32x32x16_bf16(va1, pb[kc], O1, 0, 0, 0);
      }
      __builtin_amdgcn_s_setprio(0);
    }

    __builtin_amdgcn_s_barrier();            // all waves done reading buf cur
    if (kt + 2 <= tendB) STAGE(cur, kt + 2)  // overwrite now safe; 2 tiles to land
  }

  l += __shfl_xor(l, 32);
  const float inv = 1.f / l;
  const int s = qbase + q31;
  u16* dst = AO + ((size_t)(b * SEQ + s) * NH + h) * 64;
#pragma unroll
  for (int rp = 0; rp < 8; ++rp) {
    const int r = rp * 2;
    const int d = (r & 3) + 8 * (r >> 2) + 4 * hiL;
    u32 w0, w1;
    asm("v_cvt_pk_bf16_f32 %0, %1, %2" : "=v"(w0) : "v"(O0[r] * inv), "v"(O0[r + 1] * inv));
    asm("v_cvt_pk_bf16_f32 %0, %1, %2" : "=v"(w1) : "v"(O1[r] * inv), "v"(O1[r + 1] * inv));
    *reinterpret_cast<u32*>(dst + d) = w0;
    *reinterpret_cast<u32*>(dst + 32 + d) = w1;
  }
}

extern "C" void kernel_launch(void* const* d_in, const int* in_sizes, int n_in,
                              void* d_out, int out_size, void* d_ws, size_t ws_size,
                              hipStream_t stream) {
  const float* x  = (const float*)d_in[0];
  const int*   pos = (const int*)d_in[1];
  const float* Wq = (const float*)d_in[2];
  const float* Wk = (const float*)d_in[3];
  const float* Wv = (const float*)d_in[4];
  const float* Wo = (const float*)d_in[5];
  float* out = (float*)d_out;
  char* ws = (char*)d_ws;
  const size_t MB = 1024 * 1024;
  if (ws_size < 73 * MB) return;  // refuse to scribble OOB

  u16* xb  = (u16*)(ws);             // 16MB; re-used as AO after QKV proj
  u16* wqb = (u16*)(ws + 16 * MB);
  u16* wkb = (u16*)(ws + 18 * MB);
  u16* wvb = (u16*)(ws + 20 * MB);
  u16* wob = (u16*)(ws + 22 * MB);
  u16* Qh  = (u16*)(ws + 24 * MB);
  u16* Kh  = (u16*)(ws + 40 * MB);
  u16* Vt  = (u16*)(ws + 56 * MB);
  float2* tab = (float2*)(ws + 72 * MB);
  u16* AO = xb;

  const int NPREP = MTOT * DM / 4 + 4 * (DM * DM / 4) + SEQ * 32;
  prep_k<<<(NPREP + 255) / 256, 256, 0, stream>>>(x, Wq, Wk, Wv, Wo, pos,
                                                  xb, wqb, wkb, wvb, wob, tab);
  // grid: x = m-tile (64), y = n-tile (8), z = matrix -> xcd = m%8 (A-panel local)
  gemm_bt<1><<<dim3(64, 8, 3), 256, 0, stream>>>(xb, wqb, wkb, wvb, nullptr, Qh, Kh, Vt, tab);
  attn_k<<<dim3(512), 512, 0, stream>>>(Qh, Kh, Vt, AO);
  gemm_bt<0><<<dim3(64, 8, 1), 256, 0, stream>>>(AO, wob, wob, wob, out, nullptr, nullptr, nullptr, nullptr);
}

// Round 22
// 200.938 us; speedup vs baseline: 1.1659x; 1.0148x over previous
//
#include <hip/hip_runtime.h>

#define SEQ   2048
#define BATCH 4
#define NH    16
#define DM    1024
#define MTOT  (BATCH*SEQ)   // 8192

typedef unsigned short u16;
typedef unsigned int   u32;
typedef __attribute__((ext_vector_type(8)))  __bf16 bf16x8;
typedef __attribute__((ext_vector_type(4)))  float  f32x4;
typedef __attribute__((ext_vector_type(16))) float  f32x16;
typedef __attribute__((address_space(1))) u32 as1_u32;
typedef __attribute__((address_space(3))) u32 as3_u32;

__device__ __forceinline__ u16 f2bf(float f) {
  union { float f; u32 u; } c; c.f = f;
  return (u16)((c.u + 0x7fffu + ((c.u >> 16) & 1u)) >> 16);
}

// Fused front-end: all four weight casts + x cast + RoPE table in ONE launch.
__global__ __launch_bounds__(256)
void prep_k(const float* __restrict__ x,  const float* __restrict__ Wq,
            const float* __restrict__ Wk, const float* __restrict__ Wv,
            const float* __restrict__ Wo, const int* __restrict__ pos,
            u16* __restrict__ xb,  u16* __restrict__ wqb, u16* __restrict__ wkb,
            u16* __restrict__ wvb, u16* __restrict__ wob, float2* __restrict__ tab) {
  const int NX4 = MTOT * DM / 4;   // 2097152
  const int NW4 = DM * DM / 4;     // 262144
  const int i = blockIdx.x * blockDim.x + threadIdx.x;
  int j = i;
  const float* src = nullptr; u16* dst = nullptr;
  if (j < NX4) { src = x; dst = xb; }
  else {
    j -= NX4;
    if (j < NW4) { src = Wq; dst = wqb; }
    else if (j < 2 * NW4) { src = Wk; dst = wkb; j -= NW4; }
    else if (j < 3 * NW4) { src = Wv; dst = wvb; j -= 2 * NW4; }
    else if (j < 4 * NW4) { src = Wo; dst = wob; j -= 3 * NW4; }
    else {
      j -= 4 * NW4;
      if (j < SEQ * 32) {
        const int s = j >> 5, jj = j & 31;
        const float p = (float)pos[s];
        const float fr = powf(10000.f, -(float)jj / 32.f);
        tab[j] = make_float2(cosf(p * fr), sinf(p * fr));
      }
      return;
    }
  }
  float4 v = reinterpret_cast<const float4*>(src)[j];
  ushort4 o;
  o.x = f2bf(v.x); o.y = f2bf(v.y); o.z = f2bf(v.z); o.w = f2bf(v.w);
  reinterpret_cast<ushort4*>(dst)[j] = o;
}

// C = A @ Bt^T.  A: [M,1024] bf16 row-major. Bt: [1024,1024] bf16 row-major ([N][K]).
// R22: R17 config (128x128 tile, 4 waves, BK=32, 3 x 8KB buffers, counted vmcnt,
// raw s_barriers, (row>>1)&3 swizzle both sides, XCD-local grid) with the barrier
// ROUNDS HALVED: each round computes TWO staged tiles (kt from buf c, kt+1 from
// buf c+1; 16 ds_read + 32 MFMA) then restages both freed buffers. 16 rounds
// instead of 32 -> half the {wait + 2 barrier + reconvergence} fixed cost.
// Wait math: at round top only tile kt+2's stage (4 instr) is outstanding ->
// vmcnt(4); last round vmcnt(0). Tile kt+1's stage got one full (2x-length)
// round to land (R15/16: one old round already sufficed).
// EPI 0: fp32 -> outF. EPI 1: z=0/1 -> RoPE -> Qh/Kh; z=2 -> Vt.
// Q pre-scaled by 0.125*log2(e) so attention softmax runs in exp2 domain.
template<int EPI>
__global__ __launch_bounds__(256)
void gemm_bt(const u16* __restrict__ A,
             const u16* __restrict__ B0, const u16* __restrict__ B1, const u16* __restrict__ B2,
             float* __restrict__ outF,
             u16* __restrict__ Qh, u16* __restrict__ Kh, u16* __restrict__ Vt,
             const float2* __restrict__ tab) {
  const int K = DM, N = DM;
  const int NT = K / 32;           // 32 K-tiles, 16 rounds
  __shared__ u16 lsA[3][128 * 32];
  __shared__ u16 lsB[3][128 * 32];
  const int t = threadIdx.x;
  const int lane = t & 63;
  const int wid = t >> 6;
  const int wr = wid >> 1, wc = wid & 1;
  const int m0 = blockIdx.x * 128;   // x = m-tile (64) -> xcd = m%8
  const int n0 = blockIdx.y * 128;   // y = n-tile (8)
  const int z = blockIdx.z;
  const u16* Bt = (z == 0) ? B0 : (z == 1 ? B1 : B2);

  f32x4 acc[4][4] = {};

  const int l15 = lane & 15, lsl = lane >> 4;

#define STG(bf, kt_)                                                                 \
  {                                                                                  \
    _Pragma("unroll")                                                                \
    for (int p = 0; p < 2; ++p) {                                                    \
      const int idx = p * 256 + t;                                                   \
      const int row = idx >> 2;                                                      \
      const int sg = ((idx & 3) ^ ((row >> 1) & 3)) * 8;                             \
      __builtin_amdgcn_global_load_lds(                                              \
          (const as1_u32*)(A + (size_t)(m0 + row) * K + (kt_) * 32 + sg),            \
          (as3_u32*)((char*)&lsA[bf][0] + idx * 16), 16, 0, 0);                      \
      __builtin_amdgcn_global_load_lds(                                              \
          (const as1_u32*)(Bt + (size_t)(n0 + row) * K + (kt_) * 32 + sg),           \
          (as3_u32*)((char*)&lsB[bf][0] + idx * 16), 16, 0, 0);                      \
    }                                                                                \
  }

#define COMPUTE_TILE(cc)                                                             \
  {                                                                                  \
    bf16x8 af[4], bfr[4];                                                            \
    _Pragma("unroll")                                                                \
    for (int mt = 0; mt < 4; ++mt) {                                                 \
      const int r = wr * 64 + mt * 16 + l15;                                         \
      af[mt] = *(const bf16x8*)&lsA[cc][r * 32 + (lsl ^ ((r >> 1) & 3)) * 8];        \
    }                                                                                \
    _Pragma("unroll")                                                                \
    for (int nt = 0; nt < 4; ++nt) {                                                 \
      const int r = wc * 64 + nt * 16 + l15;                                         \
      bfr[nt] = *(const bf16x8*)&lsB[cc][r * 32 + (lsl ^ ((r >> 1) & 3)) * 8];       \
    }                                                                                \
    _Pragma("unroll")                                                                \
    for (int mt = 0; mt < 4; ++mt)                                                   \
      _Pragma("unroll")                                                              \
      for (int nt = 0; nt < 4; ++nt)                                                 \
        acc[mt][nt] = __builtin_amdgcn_mfma_f32_16x16x32_bf16(af[mt], bfr[nt],       \
                                                              acc[mt][nt], 0, 0, 0);\
  }

  STG(0, 0)
  STG(1, 1)
  STG(2, 2)

  int c = 0;
  for (int kt = 0; kt < NT; kt += 2) {
    const int c2 = (c == 2) ? 0 : c + 1;
    if (kt + 2 < NT) { asm volatile("s_waitcnt vmcnt(4)" ::: "memory"); }
    else             { asm volatile("s_waitcnt vmcnt(0)" ::: "memory"); }
    __builtin_amdgcn_sched_barrier(0);
    __builtin_amdgcn_s_barrier();

    COMPUTE_TILE(c)    // tile kt
    COMPUTE_TILE(c2)   // tile kt+1 (ds_reads interleave under tile kt's MFMAs)

    __builtin_amdgcn_s_barrier();            // all waves done reading bufs c, c2
    if (kt + 3 < NT) STG(c, kt + 3)          // refill both freed buffers
    if (kt + 4 < NT) STG(c2, kt + 4)
    c = (c2 == 2) ? 0 : c2 + 1;              // advance by 2 mod 3
  }
#undef COMPUTE_TILE
#undef STG

#pragma unroll
  for (int mt = 0; mt < 4; ++mt) {
    const int gmb = m0 + wr * 64 + mt * 16 + (lane >> 4) * 4;
#pragma unroll
    for (int nt = 0; nt < 4; ++nt) {
      const int gn = n0 + wc * 64 + nt * 16 + (lane & 15);
#pragma unroll
      for (int r = 0; r < 4; ++r) {
        float v = acc[mt][nt][r];
        if (EPI == 0) {
          outF[(size_t)(gmb + r) * N + gn] = v;
        } else {
          const int row = gmb + r;
          const int b = row >> 11, s = row & (SEQ - 1);
          const int h = gn >> 6, dd = gn & 63;
          if (z < 2) {
            float p = __shfl_xor(v, 1);
            const float2 cs = tab[(s << 5) + (dd >> 1)];
            float o = ((lane & 1) == 0) ? (v * cs.x - p * cs.y) : (p * cs.y + v * cs.x);
            if (z == 0) o *= 0.18033688011112042f;  // 0.125 * log2(e)
            u16* dst = z ? Kh : Qh;
            dst[((size_t)((b * NH + h) * SEQ + s) << 6) + dd] = f2bf(o);
          } else {
            Vt[((size_t)((b * NH + h) << 6) + dd) * SEQ + s] = f2bf(v);
          }
        }
      }
    }
  }
}

// Flash attention, causal, log2-domain softmax, SWAPPED-OPERAND 32x32x16 MFMA
// (in-register softmax) + block-shared LDS K/V staging via global_load_lds with
// XOR swizzle; 2-tile-deep staging, counted vmcnt(2/0), raw s_barriers.
// 8-wave blocks (512 thr) owning 256 q-rows; 32KB LDS; grid 512 = 64 bh x 8
// ranks; bid%8 = bh%8 (XCD-local). Complementary chunk pairing (R21, neutral)
// and setprio (R20, neutral) kept. ~62us measured.
__global__ __launch_bounds__(512)
void attn_k(const u16* __restrict__ Qh, const u16* __restrict__ Kh,
            const u16* __restrict__ Vt, u16* __restrict__ AO) {
  __shared__ u16 lsK[2][64 * 64];
  __shared__ u16 lsV[2][64 * 64];
  const int t = threadIdx.x, lane = t & 63, w = t >> 6;   // w in [0,8)
  const int hiL = lane >> 5;
  const int q31 = lane & 31;
  const int bid = blockIdx.x;
  const int bh = bid & 63, b = bh >> 4, h = bh & 15;
  const int rank = bid >> 6;                  // [0,8)
  const int chunk_blk = (rank < 4) ? (7 - rank) : (rank - 4);  // complementary pairs
  const int qb_blk = chunk_blk * 256;
  const int tendB = (qb_blk + 255) >> 6;      // >= 3 always
  const int qbase = qb_blk + w * 32;          // this wave's 32 q-rows
  const int tendW = (qbase + 31) >> 6;
  const u16* Qp = Qh + (size_t)bh * SEQ * 64;
  const u16* Kp = Kh + (size_t)bh * SEQ * 64;
  const u16* Vp = Vt + (size_t)bh * 64 * SEQ;

  bf16x8 qa[4];
#pragma unroll
  for (int kc = 0; kc < 4; ++kc)
    qa[kc] = *(const bf16x8*)(Qp + (size_t)(qbase + q31) * 64 + kc * 16 + hiL * 8);

  f32x16 O0 = {}, O1 = {};
  float m = -1e30f, l = 0.f;

#define STAGE(bf, kt_)                                                                  \
  {                                                                                     \
    const int k0s = (kt_) * 64;                                                         \
    const int row = t >> 3;                                                             \
    const int cb = ((t & 7) << 4) ^ ((row & 7) << 4);                                   \
    __builtin_amdgcn_global_load_lds((const as1_u32*)(Kp + (size_t)(k0s + row) * 64 + (cb >> 1)), \
                                     (as3_u32*)((char*)&lsK[bf][0] + t * 16), 16, 0, 0); \
    __builtin_amdgcn_global_load_lds((const as1_u32*)(Vp + (size_t)row * SEQ + k0s + (cb >> 1)), \
                                     (as3_u32*)((char*)&lsV[bf][0] + t * 16), 16, 0, 0); \
  }

  STAGE(0, 0)
  STAGE(1, 1)

  for (int kt = 0; kt <= tendB; ++kt) {
    const int cur = kt & 1;
    const int rem = tendB - kt;
    if (rem >= 1) { asm volatile("s_waitcnt vmcnt(2)" ::: "memory"); }
    else          { asm volatile("s_waitcnt vmcnt(0)" ::: "memory"); }
    __builtin_amdgcn_sched_barrier(0);
    __builtin_amdgcn_s_barrier();

    if (kt <= tendW) {
      const int k0 = kt * 64;
      const int swz = (q31 & 7) << 4;

      f32x16 S0 = {}, S1 = {};
      __builtin_amdgcn_s_setprio(1);
#pragma unroll
      for (int kc = 0; kc < 4; ++kc) {
        const int cb = (kc * 32 + hiL * 16) ^ swz;
        bf16x8 ka = *(const bf16x8*)&lsK[cur][q31 * 64 + (cb >> 1)];
        S0 = __builtin_amdgcn_mfma_f32_32x32x16_bf16(ka, qa[kc], S0, 0, 0, 0);
      }
#pragma unroll
      for (int kc = 0; kc < 4; ++kc) {
        const int cb = (kc * 32 + hiL * 16) ^ swz;
        bf16x8 ka = *(const bf16x8*)&lsK[cur][(32 + q31) * 64 + (cb >> 1)];
        S1 = __builtin_amdgcn_mfma_f32_32x32x16_bf16(ka, qa[kc], S1, 0, 0, 0);
      }
      __builtin_amdgcn_s_setprio(0);

      if (kt == tendW) {
        const int qg = qbase + q31;
#pragma unroll
        for (int r = 0; r < 16; ++r) {
          const int kg = k0 + (r & 3) + 8 * (r >> 2) + 4 * hiL;
          S0[r] = (kg > qg) ? -1e30f : S0[r];
          S1[r] = (kg + 32 > qg) ? -1e30f : S1[r];
        }
      }

      float vmax = -1e30f;
#pragma unroll
      for (int r = 0; r < 16; ++r) {
        vmax = fmaxf(vmax, S0[r]);
        vmax = fmaxf(vmax, S1[r]);
      }
      vmax = fmaxf(vmax, __shfl_xor(vmax, 32));

      if (vmax > m + 7.f) {    // defer-max (T13), log2 domain
        const float al = exp2f(m - vmax);
        m = vmax; l *= al;
#pragma unroll
        for (int r = 0; r < 16; ++r) { O0[r] *= al; O1[r] *= al; }
      }

      float rs = 0.f;
#pragma unroll
      for (int r = 0; r < 16; ++r) {
        const float p0 = exp2f(S0[r] - m);
        const float p1 = exp2f(S1[r] - m);
        S0[r] = p0; S1[r] = p1;
        rs += p0 + p1;
      }
      l += rs;

      bf16x8 pb[4];
#define PACKKC(SV, kb, OUT)                                                         \
      {                                                                             \
        u32 qL0, qL1, qH0, qH1;                                                     \
        asm("v_cvt_pk_bf16_f32 %0, %1, %2" : "=v"(qL0) : "v"(SV[8*(kb)+0]), "v"(SV[8*(kb)+1])); \
        asm("v_cvt_pk_bf16_f32 %0, %1, %2" : "=v"(qL1) : "v"(SV[8*(kb)+2]), "v"(SV[8*(kb)+3])); \
        asm("v_cvt_pk_bf16_f32 %0, %1, %2" : "=v"(qH0) : "v"(SV[8*(kb)+4]), "v"(SV[8*(kb)+5])); \
        asm("v_cvt_pk_bf16_f32 %0, %1, %2" : "=v"(qH1) : "v"(SV[8*(kb)+6]), "v"(SV[8*(kb)+7])); \
        const u32 sA = hiL ? qL0 : qH0;                                             \
        const u32 sB = hiL ? qL1 : qH1;                                             \
        const u32 rA = (u32)__shfl_xor((int)sA, 32);                                \
        const u32 rB = (u32)__shfl_xor((int)sB, 32);                                \
        union { u32 wds[4]; bf16x8 v; } uu;                                         \
        uu.wds[0] = hiL ? rA : qL0;                                                 \
        uu.wds[1] = hiL ? rB : qL1;                                                 \
        uu.wds[2] = hiL ? qH0 : rA;                                                 \
        uu.wds[3] = hiL ? qH1 : rB;                                                 \
        OUT = uu.v;                                                                 \
      }
      PACKKC(S0, 0, pb[0])
      PACKKC(S0, 1, pb[1])
      PACKKC(S1, 0, pb[2])
      PACKKC(S1, 1, pb[3])
#undef PACKKC

      __builtin_amdgcn_s_setprio(1);
#pragma unroll
      for (int kc = 0; kc < 4; ++kc) {
        const int cb = (kc * 32 + hiL * 16) ^ swz;
        bf16x8 va0 = *(const bf16x8*)&lsV[cur][q31 * 64 + (cb >> 1)];
        bf16x8 va1 = *(const bf16x8*)&lsV[cur][(32 + q31) * 64 + (cb >> 1)];
        O0 = __builtin_amdgcn_mfma_f32_32x32x16_bf16(va0, pb[kc], O0, 0, 0, 0);
        O1 = __builtin_amdgcn_mfma_f32_32x32x16_bf16(va1, pb[kc], O1, 0, 0, 0);
      }
      __builtin_amdgcn_s_setprio(0);
    }

    __builtin_amdgcn_s_barrier();            // all waves done reading buf cur
    if (kt + 2 <= tendB) STAGE(cur, kt + 2)  // overwrite now safe; 2 tiles to land
  }

  l += __shfl_xor(l, 32);
  const float inv = 1.f / l;
  const int s = qbase + q31;
  u16* dst = AO + ((size_t)(b * SEQ + s) * NH + h) * 64;
#pragma unroll
  for (int rp = 0; rp < 8; ++rp) {
    const int r = rp * 2;
    const int d = (r & 3) + 8 * (r >> 2) + 4 * hiL;
    u32 w0, w1;
    asm("v_cvt_pk_bf16_f32 %0, %1, %2" : "=v"(w0) : "v"(O0[r] * inv), "v"(O0[r + 1] * inv));
    asm("v_cvt_pk_bf16_f32 %0, %1, %2" : "=v"(w1) : "v"(O1[r] * inv), "v"(O1[r + 1] * inv));
    *reinterpret_cast<u32*>(dst + d) = w0;
    *reinterpret_cast<u32*>(dst + 32 + d) = w1;
  }
}

extern "C" void kernel_launch(void* const* d_in, const int* in_sizes, int n_in,
                              void* d_out, int out_size, void* d_ws, size_t ws_size,
                              hipStream_t stream) {
  const float* x  = (const float*)d_in[0];
  const int*   pos = (const int*)d_in[1];
  const float* Wq = (const float*)d_in[2];
  const float* Wk = (const float*)d_in[3];
  const float* Wv = (const float*)d_in[4];
  const float* Wo = (const float*)d_in[5];
  float* out = (float*)d_out;
  char* ws = (char*)d_ws;
  const size_t MB = 1024 * 1024;
  if (ws_size < 73 * MB) return;  // refuse to scribble OOB

  u16* xb  = (u16*)(ws);             // 16MB; re-used as AO after QKV proj
  u16* wqb = (u16*)(ws + 16 * MB);
  u16* wkb = (u16*)(ws + 18 * MB);
  u16* wvb = (u16*)(ws + 20 * MB);
  u16* wob = (u16*)(ws + 22 * MB);
  u16* Qh  = (u16*)(ws + 24 * MB);
  u16* Kh  = (u16*)(ws + 40 * MB);
  u16* Vt  = (u16*)(ws + 56 * MB);
  float2* tab = (float2*)(ws + 72 * MB);
  u16* AO = xb;

  const int NPREP = MTOT * DM / 4 + 4 * (DM * DM / 4) + SEQ * 32;
  prep_k<<<(NPREP + 255) / 256, 256, 0, stream>>>(x, Wq, Wk, Wv, Wo, pos,
                                                  xb, wqb, wkb, wvb, wob, tab);
  // grid: x = m-tile (64), y = n-tile (8), z = matrix -> xcd = m%8 (A-panel local)
  gemm_bt<1><<<dim3(64, 8, 3), 256, 0, stream>>>(xb, wqb, wkb, wvb, nullptr, Qh, Kh, Vt, tab);
  attn_k<<<dim3(512), 512, 0, stream>>>(Qh, Kh, Vt, AO);
  gemm_bt<0><<<dim3(64, 8, 1), 256, 0, stream>>>(AO, wob, wob, wob, out, nullptr, nullptr, nullptr, nullptr);
}